// Round 1
// baseline (868.945 us; speedup 1.0000x reference)
//
#include <hip/hip_runtime.h>
#include <hip/hip_bf16.h>
#include <cstdint>
#include <cstddef>

// CFnetFilter: w_ij = segment_sum(ssp(ssp(dijk@W1+b1)@W2+b2), seg_j)
// ssp(x) = softplus(x) - log(2)

typedef float f32x4 __attribute__((ext_vector_type(4)));
typedef __bf16 bf16x8 __attribute__((ext_vector_type(8)));

static constexpr int   N_TRIPLES = 2000000;
static constexpr int   DIM       = 128;
static constexpr int   NSEG      = 100000;
static constexpr int   ROWS      = 128;     // rows per block (2e6 / 128 = 15625 exact)
static constexpr float LOG2F_    = 0.6931471805599453f;

__device__ __forceinline__ float ssp(float x) {
  // stable softplus(x) - log2
  float e = __expf(-fabsf(x));
  return fmaxf(x, 0.0f) + __logf(1.0f + e) - LOG2F_;
}

// Transpose W1,W2 [k][n] f32 -> WT [n][k] bf16 (so MFMA B-frags are contiguous in k)
__global__ void wt_kernel(const float* __restrict__ W1, const float* __restrict__ W2,
                          __bf16* __restrict__ WT) {
  int t = blockIdx.x * 256 + threadIdx.x;   // 0..16383
  int k = t >> 7;
  int n = t & 127;
  WT[n * 128 + k]         = (__bf16)W1[t];
  WT[16384 + n * 128 + k] = (__bf16)W2[t];
}

__global__ __launch_bounds__(256, 4) void fused_kernel(
    const float* __restrict__ dijk, const int* __restrict__ seg,
    const __bf16* __restrict__ WT,
    const float* __restrict__ b1v, const float* __restrict__ b2v,
    float* __restrict__ out)
{
  __shared__ __bf16 hbuf[ROWS * DIM];   // 32 KB, XOR-swizzled rows; reused for wijk
  __shared__ int seg_lds[ROWS];

  const int tid  = threadIdx.x;
  const int lane = tid & 63;
  const int wave = tid >> 6;
  const int l15  = lane & 15;
  const int g    = lane >> 4;           // quarter-wave group (k-group for A/B frags)
  const int r0   = blockIdx.x * ROWS;
  const int wrow = wave * 32;           // this wave's first row within the block

  if (tid < ROWS) seg_lds[tid] = seg[r0 + tid];

  // biases for this lane's 8 column slots (col = nt*16 + l15)
  float bias1[8], bias2[8];
  #pragma unroll
  for (int nt = 0; nt < 8; ++nt) {
    bias1[nt] = b1v[nt * 16 + l15];
    bias2[nt] = b2v[nt * 16 + l15];
  }

  char* hb = (char*)hbuf;

  // ---------------- GEMM1: h = ssp(dijk @ W1 + b1) ----------------
  f32x4 acc[2][8] = {};
  {
    const __bf16* WT1 = WT;
    #pragma unroll
    for (int ks = 0; ks < 4; ++ks) {
      bf16x8 afrag[2];
      #pragma unroll
      for (int mt = 0; mt < 2; ++mt) {
        const float* p = dijk + (size_t)(r0 + wrow + mt * 16 + l15) * DIM + ks * 32 + g * 8;
        f32x4 v0 = *(const f32x4*)p;
        f32x4 v1 = *(const f32x4*)(p + 4);
        bf16x8 t8;
        t8[0] = (__bf16)v0[0]; t8[1] = (__bf16)v0[1]; t8[2] = (__bf16)v0[2]; t8[3] = (__bf16)v0[3];
        t8[4] = (__bf16)v1[0]; t8[5] = (__bf16)v1[1]; t8[6] = (__bf16)v1[2]; t8[7] = (__bf16)v1[3];
        afrag[mt] = t8;
      }
      #pragma unroll
      for (int nt = 0; nt < 8; ++nt) {
        bf16x8 bfrag = *(const bf16x8*)(WT1 + (nt * 16 + l15) * DIM + ks * 32 + g * 8);
        acc[0][nt] = __builtin_amdgcn_mfma_f32_16x16x32_bf16(afrag[0], bfrag, acc[0][nt], 0, 0, 0);
        acc[1][nt] = __builtin_amdgcn_mfma_f32_16x16x32_bf16(afrag[1], bfrag, acc[1][nt], 0, 0, 0);
      }
    }
  }

  // bias + ssp, store h to LDS (bf16, swizzled). Each wave writes only its own
  // 32 rows and GEMM2 reads only those rows -> no barrier needed (in-wave lgkmcnt order).
  #pragma unroll
  for (int mt = 0; mt < 2; ++mt) {
    #pragma unroll
    for (int nt = 0; nt < 8; ++nt) {
      #pragma unroll
      for (int j = 0; j < 4; ++j) {
        int row = wrow + mt * 16 + g * 4 + j;   // C/D layout: row=(lane>>4)*4+j
        int col = nt * 16 + l15;                //            col=lane&15
        float hv = ssp(acc[mt][nt][j] + bias1[nt]);
        *(__bf16*)(hb + row * 256 + ((col * 2) ^ ((row & 7) << 4))) = (__bf16)hv;
      }
    }
  }

  // ---------------- GEMM2: w = ssp(h @ W2 + b2) ----------------
  f32x4 acc2[2][8] = {};
  {
    const __bf16* WT2 = WT + 16384;
    #pragma unroll
    for (int ks = 0; ks < 4; ++ks) {
      bf16x8 afrag[2];
      #pragma unroll
      for (int mt = 0; mt < 2; ++mt) {
        int row = wrow + mt * 16 + l15;         // A layout: row=lane&15
        int kb  = (ks * 64 + g * 16) ^ ((row & 7) << 4);
        afrag[mt] = *(const bf16x8*)(hb + row * 256 + kb);
      }
      #pragma unroll
      for (int nt = 0; nt < 8; ++nt) {
        bf16x8 bfrag = *(const bf16x8*)(WT2 + (nt * 16 + l15) * DIM + ks * 32 + g * 8);
        acc2[0][nt] = __builtin_amdgcn_mfma_f32_16x16x32_bf16(afrag[0], bfrag, acc2[0][nt], 0, 0, 0);
        acc2[1][nt] = __builtin_amdgcn_mfma_f32_16x16x32_bf16(afrag[1], bfrag, acc2[1][nt], 0, 0, 0);
      }
    }
  }

  // bias + ssp, store wijk into the same LDS buffer (own-wave rows; reads above are done)
  #pragma unroll
  for (int mt = 0; mt < 2; ++mt) {
    #pragma unroll
    for (int nt = 0; nt < 8; ++nt) {
      #pragma unroll
      for (int j = 0; j < 4; ++j) {
        int row = wrow + mt * 16 + g * 4 + j;
        int col = nt * 16 + l15;
        float wv = ssp(acc2[mt][nt][j] + bias2[nt]);
        *(__bf16*)(hb + row * 256 + ((col * 2) ^ ((row & 7) << 4))) = (__bf16)wv;
      }
    }
  }

  __syncthreads();   // the only block-wide barrier: wijk + seg_lds visible to all

  // ---------------- segmented reduce (seg_j sorted) ----------------
  // thread t: column (t&127), rows [hh*64, hh*64+64). Seg-change branch is
  // wave-uniform (each wave has a single hh), atomics are 64-lane contiguous.
  {
    int col = tid & 127;
    int hh  = tid >> 7;
    int rbeg = hh * 64;
    float accum = 0.0f;
    int cur = seg_lds[rbeg];
    for (int i = 0; i < 64; ++i) {
      int row = rbeg + i;
      int s = seg_lds[row];
      if (s != cur) {
        atomicAdd(out + (size_t)cur * DIM + col, accum);
        accum = 0.0f;
        cur = s;
      }
      float wv = (float)*(const __bf16*)(hb + row * 256 + ((col * 2) ^ ((row & 7) << 4)));
      accum += wv;
    }
    atomicAdd(out + (size_t)cur * DIM + col, accum);
  }
}

extern "C" void kernel_launch(void* const* d_in, const int* in_sizes, int n_in,
                              void* d_out, int out_size, void* d_ws, size_t ws_size,
                              hipStream_t stream) {
  const float* dijk = (const float*)d_in[0];
  const int*   seg  = (const int*)d_in[1];
  const float* W1   = (const float*)d_in[2];
  const float* b1   = (const float*)d_in[3];
  const float* W2   = (const float*)d_in[4];
  const float* b2   = (const float*)d_in[5];
  float* out = (float*)d_out;
  __bf16* WT = (__bf16*)d_ws;   // 2 * 128*128 bf16 = 64 KB

  // empty segments must be exactly 0; harness doesn't re-poison between replays
  hipMemsetAsync(out, 0, (size_t)NSEG * DIM * sizeof(float), stream);

  wt_kernel<<<64, 256, 0, stream>>>(W1, W2, WT);

  fused_kernel<<<N_TRIPLES / ROWS, 256, 0, stream>>>(dijk, seg, WT, b1, b2, out);
}